// Round 1
// baseline (270.699 us; speedup 1.0000x reference)
//
#include <hip/hip_runtime.h>
#include <hip/hip_bf16.h>

#define NH 16
#define QL 2048
#define KVL 4096
#define DHEAD 64
#define PREFIX (KVL - QL)
#define QT 64            // q rows per workgroup
#define KB 32            // kv rows per iteration
#define SCALE 0.125f

typedef __attribute__((ext_vector_type(8))) short short8;
typedef __attribute__((ext_vector_type(4))) float f32x4;

#define KSTR 72          // 64 + 8 pad (ushort units) -> 2-way-free b128 reads
#define VSTR 40          // 32 + 8 pad
#define PSTR 40          // 32 + 8 pad

__device__ __forceinline__ ushort f2bf(float x) {
    union { float f; unsigned int u; } v; v.f = x;
    unsigned int r = v.u + 0x7fffu + ((v.u >> 16) & 1u);   // RTNE
    return (ushort)(r >> 16);
}
__device__ __forceinline__ float bf2f(ushort h) {
    union { unsigned int u; float f; } v; v.u = ((unsigned int)h) << 16;
    return v.f;
}

__global__ __launch_bounds__(256, 2)
void sdpa_fwd(const float* __restrict__ Q, const float* __restrict__ K,
              const float* __restrict__ V, float* __restrict__ O)
{
    __shared__ ushort sKh[KB][KSTR];
    __shared__ ushort sKl[KB][KSTR];
    __shared__ ushort sVt[DHEAD][VSTR];
    __shared__ ushort sP[4][16][PSTR];

    const int tid  = threadIdx.x;
    const int lane = tid & 63;
    const int w    = tid >> 6;
    const int h    = blockIdx.y;
    const int q0   = blockIdx.x * QT;
    const int qb   = q0 + w * 16;        // this wave's q base

    const int lrow = lane & 15;
    const int lgrp = lane >> 4;          // 0..3

    // ---- preload Q fragments (pre-scaled), hi/lo split ----
    short8 qh[2], ql[2];
    {
        const float* qp = Q + ((size_t)h * QL + (qb + lrow)) * DHEAD;
        #pragma unroll
        for (int dh = 0; dh < 2; ++dh) {
            const int d0 = dh * 32 + lgrp * 8;
            #pragma unroll
            for (int j = 0; j < 8; ++j) {
                float x = qp[d0 + j] * SCALE;
                ushort hb = f2bf(x);
                float  hf = bf2f(hb);
                ushort lb = f2bf(x - hf);
                qh[dh][j] = (short)hb;
                ql[dh][j] = (short)lb;
            }
        }
    }

    f32x4 oacc[4];
    float m_r[4], l_r[4];
    #pragma unroll
    for (int n = 0; n < 4; ++n) { oacc[n][0]=0.f; oacc[n][1]=0.f; oacc[n][2]=0.f; oacc[n][3]=0.f; }
    #pragma unroll
    for (int r = 0; r < 4; ++r) { m_r[r] = -1e30f; l_r[r] = 0.f; }

    const int nkv = min(KVL, PREFIX + q0 + QT);

    for (int kv0 = 0; kv0 < nkv; kv0 += KB) {
        __syncthreads();   // protect LDS reuse from previous iteration
        // ---- cooperative staging: K (hi/lo bf16) and V^T (bf16) ----
        {
            const int r  = tid >> 3;          // 0..31 kv row
            const int d0 = (tid & 7) * 8;     // 0..56
            const float* kp = K + ((size_t)h * KVL + (kv0 + r)) * DHEAD + d0;
            const float* vp = V + ((size_t)h * KVL + (kv0 + r)) * DHEAD + d0;
            short8 vh, vl;
            #pragma unroll
            for (int j = 0; j < 8; ++j) {
                float x = kp[j];
                ushort hb = f2bf(x);
                float  hf = bf2f(hb);
                vh[j] = (short)hb;
                vl[j] = (short)f2bf(x - hf);
            }
            *(short8*)&sKh[r][d0] = vh;
            *(short8*)&sKl[r][d0] = vl;
            #pragma unroll
            for (int j = 0; j < 8; ++j)
                sVt[d0 + j][r] = f2bf(vp[j]);
        }
        __syncthreads();

        // ---- S = (Q*scale) K^T, split precision: Qh*Kh + Qh*Kl + Ql*Kh ----
        f32x4 s[2];
        #pragma unroll
        for (int t = 0; t < 2; ++t) { s[t][0]=0.f; s[t][1]=0.f; s[t][2]=0.f; s[t][3]=0.f; }
        #pragma unroll
        for (int t = 0; t < 2; ++t) {
            #pragma unroll
            for (int dh = 0; dh < 2; ++dh) {
                const short8 kh = *(const short8*)&sKh[t*16 + lrow][dh*32 + lgrp*8];
                const short8 kl = *(const short8*)&sKl[t*16 + lrow][dh*32 + lgrp*8];
                s[t] = __builtin_amdgcn_mfma_f32_16x16x32_bf16(qh[dh], kh, s[t], 0, 0, 0);
                s[t] = __builtin_amdgcn_mfma_f32_16x16x32_bf16(qh[dh], kl, s[t], 0, 0, 0);
                s[t] = __builtin_amdgcn_mfma_f32_16x16x32_bf16(ql[dh], kh, s[t], 0, 0, 0);
            }
        }

        // ---- causal mask (only near the boundary for this wave) ----
        if (kv0 + KB > PREFIX + qb) {
            #pragma unroll
            for (int t = 0; t < 2; ++t)
                #pragma unroll
                for (int r = 0; r < 4; ++r) {
                    const int kv = kv0 + t*16 + lrow;
                    const int q  = qb + lgrp*4 + r;
                    if (kv > PREFIX + q) s[t][r] = -1e30f;
                }
        }

        // ---- online softmax (rows q = qb + lgrp*4 + r; cols spread over 16 lanes) ----
        float tmax[4];
        #pragma unroll
        for (int r = 0; r < 4; ++r) tmax[r] = fmaxf(s[0][r], s[1][r]);
        #pragma unroll
        for (int off = 1; off <= 8; off <<= 1)
            #pragma unroll
            for (int r = 0; r < 4; ++r) tmax[r] = fmaxf(tmax[r], __shfl_xor(tmax[r], off, 64));

        float f[4];
        #pragma unroll
        for (int r = 0; r < 4; ++r) {
            const float mn = fmaxf(m_r[r], tmax[r]);
            f[r] = __expf(m_r[r] - mn);
            m_r[r] = mn;
        }
        #pragma unroll
        for (int t = 0; t < 2; ++t)
            #pragma unroll
            for (int r = 0; r < 4; ++r) s[t][r] = __expf(s[t][r] - m_r[r]);

        float rs[4];
        #pragma unroll
        for (int r = 0; r < 4; ++r) rs[r] = s[0][r] + s[1][r];
        #pragma unroll
        for (int off = 1; off <= 8; off <<= 1)
            #pragma unroll
            for (int r = 0; r < 4; ++r) rs[r] += __shfl_xor(rs[r], off, 64);
        #pragma unroll
        for (int r = 0; r < 4; ++r) l_r[r] = l_r[r] * f[r] + rs[r];
        #pragma unroll
        for (int n = 0; n < 4; ++n)
            #pragma unroll
            for (int r = 0; r < 4; ++r) oacc[n][r] *= f[r];

        // ---- P -> bf16 -> LDS (wave-private), transpose into A-frag layout ----
        #pragma unroll
        for (int t = 0; t < 2; ++t)
            #pragma unroll
            for (int r = 0; r < 4; ++r)
                sP[w][lgrp*4 + r][t*16 + lrow] = f2bf(s[t][r]);
        asm volatile("s_waitcnt lgkmcnt(0)" ::: "memory");
        __builtin_amdgcn_sched_barrier(0);

        const short8 pa = *(const short8*)&sP[w][lrow][lgrp*8];
        #pragma unroll
        for (int n = 0; n < 4; ++n) {
            const short8 vb = *(const short8*)&sVt[n*16 + lrow][lgrp*8];
            oacc[n] = __builtin_amdgcn_mfma_f32_16x16x32_bf16(pa, vb, oacc[n], 0, 0, 0);
        }
    }

    // ---- epilogue: O = acc / l ----
    float inv[4];
    #pragma unroll
    for (int r = 0; r < 4; ++r) inv[r] = 1.0f / l_r[r];
    float* op = O + ((size_t)h * QL + qb) * DHEAD;
    #pragma unroll
    for (int n = 0; n < 4; ++n)
        #pragma unroll
        for (int r = 0; r < 4; ++r)
            op[(lgrp*4 + r) * DHEAD + n*16 + lrow] = oacc[n][r] * inv[r];
}

extern "C" void kernel_launch(void* const* d_in, const int* in_sizes, int n_in,
                              void* d_out, int out_size, void* d_ws, size_t ws_size,
                              hipStream_t stream) {
    const float* Q = (const float*)d_in[0];
    const float* K = (const float*)d_in[1];
    const float* V = (const float*)d_in[2];
    // d_in[3] = attn_mask: causal-prefix mask reproduced analytically, not read.
    float* O = (float*)d_out;
    dim3 grid(QL / QT, NH);
    dim3 block(256);
    hipLaunchKernelGGL(sdpa_fwd, grid, block, 0, stream, Q, K, V, O);
}

// Round 2
// 162.538 us; speedup vs baseline: 1.6654x; 1.6654x over previous
//
#include <hip/hip_runtime.h>
#include <hip/hip_bf16.h>

#define NH 16
#define QL 2048
#define KVL 4096
#define DH 64
#define PREFIX (KVL - QL)
#define KB 64
#define NTILES (KVL / KB)          // 64
#define TILE_US 12288              // ushorts/tile: Kh 4096 | Kl 4096 | Vt 4096
#define SCALE 0.125f

typedef __attribute__((ext_vector_type(8))) short short8;
typedef __attribute__((ext_vector_type(4))) float f32x4;
typedef unsigned int u32;

static __device__ __forceinline__ ushort f2bf(float x) {
    union { float f; u32 u; } v; v.f = x;
    u32 r = v.u + 0x7fffu + ((v.u >> 16) & 1u);   // RTNE
    return (ushort)(r >> 16);
}
static __device__ __forceinline__ float bf2f(ushort h) {
    union { u32 u; float f; } v; v.u = ((u32)h) << 16;
    return v.f;
}
static __device__ __forceinline__ void gload_lds16(const ushort* g, ushort* l) {
    __builtin_amdgcn_global_load_lds(
        (const __attribute__((address_space(1))) u32*)g,
        (__attribute__((address_space(3))) u32*)l, 16, 0, 0);
}

// ---- precompute: K -> Kh/Kl bf16, tile-blocked [h][tile][kv 64][chunk^swz], ----
// ---- swizzle chunk' = chunk ^ (row&7) so LDS-linear staging yields swz layout ----
__global__ void convK(const float* __restrict__ K, ushort* __restrict__ wsKV) {
    const int gid = blockIdx.x * 256 + threadIdx.x;   // 16*4096*8 = 524288
    const int c8 = gid & 7;
    const int kv = (gid >> 3) & (KVL - 1);
    const int h  = gid >> 15;
    const float* src = K + ((size_t)h * KVL + kv) * DH + c8 * 8;
    const float4 a = *(const float4*)src;
    const float4 b = *(const float4*)(src + 4);
    const float v[8] = {a.x, a.y, a.z, a.w, b.x, b.y, b.z, b.w};
    short8 hi, lo;
    #pragma unroll
    for (int j = 0; j < 8; ++j) {
        const ushort hb = f2bf(v[j]);
        hi[j] = (short)hb;
        lo[j] = (short)f2bf(v[j] - bf2f(hb));
    }
    const int tile = kv >> 6, r = kv & 63;
    ushort* dst = wsKV + (size_t)(h * NTILES + tile) * TILE_US;
    const int off = r * 64 + ((c8 ^ (r & 7)) * 8);
    *(short8*)(dst + off) = hi;
    *(short8*)(dst + 4096 + off) = lo;
}

// ---- precompute: V -> Vt bf16 [h][tile][d 64][kvchunk^swz] (transposed) ----
__global__ void convV(const float* __restrict__ V, ushort* __restrict__ wsKV) {
    const int bx = blockIdx.x;            // h*64 + tile
    const int h = bx >> 6, tile = bx & 63;
    const int d  = threadIdx.x & 63;
    const int k8 = threadIdx.x >> 6;      // 0..7
    const float* src = V + ((size_t)h * KVL + tile * 64 + k8 * 8) * DH + d;
    short8 o;
    #pragma unroll
    for (int j = 0; j < 8; ++j) o[j] = (short)f2bf(src[j * DH]);
    ushort* dst = wsKV + (size_t)(h * NTILES + tile) * TILE_US + 8192
                + d * 64 + ((k8 ^ (d & 7)) * 8);
    *(short8*)dst = o;
}

// ---- main: 2 waves/block, 32 q rows/wave, KB=64, dbuf global_load_lds ----
__global__ __launch_bounds__(128, 1)
void sdpa_main(const float* __restrict__ Q, const ushort* __restrict__ wsKV,
               float* __restrict__ O)
{
    __shared__ ushort sKV[2][TILE_US];    // [Kh 8KB | Kl 8KB | Vt 8KB] per buf
    __shared__ ushort sP[2][32][72];      // per-wave P, 144B rows (swz-free-ish)

    const int tid  = threadIdx.x;
    const int lane = tid & 63;
    const int w    = tid >> 6;
    const int lrow = lane & 15;
    const int lgrp = lane >> 4;

    // XCD-aware mapping: 2 heads per XCD; long/short q-block pairing per head parity
    const int bid  = blockIdx.x;
    const int xcd  = bid & 7;
    const int slot = bid >> 3;            // 0..63
    const int h    = xcd * 2 + (slot >> 5);
    int qx = slot & 31;
    if (h & 1) qx = 31 - qx;
    const int q0 = qx * 64;
    const int qb = q0 + w * 32;

    // Q fragments (hi/lo split, pre-scaled)
    short8 qh[2][2], ql[2][2];
    #pragma unroll
    for (int qf = 0; qf < 2; ++qf) {
        const float* qp = Q + ((size_t)h * QL + qb + qf * 16 + lrow) * DH;
        #pragma unroll
        for (int dh = 0; dh < 2; ++dh) {
            #pragma unroll
            for (int j = 0; j < 8; ++j) {
                const float x = qp[dh * 32 + lgrp * 8 + j] * SCALE;
                const ushort hb = f2bf(x);
                qh[qf][dh][j] = (short)hb;
                ql[qf][dh][j] = (short)f2bf(x - bf2f(hb));
            }
        }
    }

    f32x4 oacc[2][4];
    #pragma unroll
    for (int qf = 0; qf < 2; ++qf)
        #pragma unroll
        for (int n = 0; n < 4; ++n)
            #pragma unroll
            for (int r = 0; r < 4; ++r) oacc[qf][n][r] = 0.f;
    float m[2] = {-1e30f, -1e30f}, l[2] = {0.f, 0.f};

    const int nt = (PREFIX + q0 + 64) / KB;
    const ushort* hbase = wsKV + (size_t)h * NTILES * TILE_US;

    // prologue stage tile 0
    #pragma unroll
    for (int k = 0; k < 12; ++k) {
        const int off = (k * 128 + tid) * 8;
        gload_lds16(hbase + off, &sKV[0][off]);
    }
    __syncthreads();

    int buf = 0;
    for (int it = 0; it < nt; ++it) {
        if (it + 1 < nt) {
            const ushort* src = hbase + (size_t)(it + 1) * TILE_US;
            #pragma unroll
            for (int k = 0; k < 12; ++k) {
                const int off = (k * 128 + tid) * 8;
                gload_lds16(src + off, &sKV[buf ^ 1][off]);
            }
        }

        // ---- QK^T swapped: sT[qf][t] holds S[kv=16t+lgrp*4+r][q=lane&15] ----
        f32x4 sT[2][4];
        #pragma unroll
        for (int qf = 0; qf < 2; ++qf)
            #pragma unroll
            for (int t = 0; t < 4; ++t)
                #pragma unroll
                for (int r = 0; r < 4; ++r) sT[qf][t][r] = 0.f;

        #pragma unroll
        for (int t = 0; t < 4; ++t) {
            const int r = t * 16 + lrow;
            #pragma unroll
            for (int dh = 0; dh < 2; ++dh) {
                const int co = r * 64 + (((dh * 4 + lgrp) ^ (lrow & 7)) * 8);
                const short8 kh = *(const short8*)&sKV[buf][co];
                const short8 kl = *(const short8*)&sKV[buf][4096 + co];
                #pragma unroll
                for (int qf = 0; qf < 2; ++qf) {
                    sT[qf][t] = __builtin_amdgcn_mfma_f32_16x16x32_bf16(kh, qh[qf][dh], sT[qf][t], 0, 0, 0);
                    sT[qf][t] = __builtin_amdgcn_mfma_f32_16x16x32_bf16(kl, qh[qf][dh], sT[qf][t], 0, 0, 0);
                    sT[qf][t] = __builtin_amdgcn_mfma_f32_16x16x32_bf16(kh, ql[qf][dh], sT[qf][t], 0, 0, 0);
                }
            }
        }

        const int kv0 = it * KB;
        #pragma unroll
        for (int qf = 0; qf < 2; ++qf) {
            const int qg = qb + qf * 16 + lrow;       // this lane's q row
            if (kv0 + KB > PREFIX + qb + qf * 16) {
                #pragma unroll
                for (int t = 0; t < 4; ++t)
                    #pragma unroll
                    for (int r = 0; r < 4; ++r)
                        if (kv0 + t * 16 + lgrp * 4 + r > PREFIX + qg) sT[qf][t][r] = -1e30f;
            }
            // scalar-per-lane online softmax (q = lane&15), 2-shuffle reductions
            float mx = sT[qf][0][0];
            #pragma unroll
            for (int t = 0; t < 4; ++t)
                #pragma unroll
                for (int r = 0; r < 4; ++r) mx = fmaxf(mx, sT[qf][t][r]);
            mx = fmaxf(mx, __shfl_xor(mx, 16));
            mx = fmaxf(mx, __shfl_xor(mx, 32));
            const float mn  = fmaxf(m[qf], mx);
            const float fsc = __expf(m[qf] - mn);
            m[qf] = mn;
            float rs = 0.f;
            #pragma unroll
            for (int t = 0; t < 4; ++t)
                #pragma unroll
                for (int r = 0; r < 4; ++r) {
                    const float p = __expf(sT[qf][t][r] - mn);
                    sT[qf][t][r] = p;
                    rs += p;
                }
            rs += __shfl_xor(rs, 16);
            rs += __shfl_xor(rs, 32);
            l[qf] = l[qf] * fsc + rs;
            #pragma unroll
            for (int rr = 0; rr < 4; ++rr) {
                const float fb = __shfl(fsc, lgrp * 4 + rr);
                #pragma unroll
                for (int n = 0; n < 4; ++n) oacc[qf][n][rr] *= fb;
            }
            // P -> bf16 pairs -> wave-private LDS [q][kv]
            #pragma unroll
            for (int t = 0; t < 4; ++t) {
                const u32 p01 = (u32)f2bf(sT[qf][t][0]) | ((u32)f2bf(sT[qf][t][1]) << 16);
                const u32 p23 = (u32)f2bf(sT[qf][t][2]) | ((u32)f2bf(sT[qf][t][3]) << 16);
                u32* pp = (u32*)&sP[w][qf * 16 + lrow][t * 16 + lgrp * 4];
                pp[0] = p01;
                pp[1] = p23;
            }
        }

        asm volatile("s_waitcnt lgkmcnt(0)" ::: "memory");
        __builtin_amdgcn_sched_barrier(0);

        // ---- PV ----
        #pragma unroll
        for (int ks = 0; ks < 2; ++ks) {
            short8 pa[2];
            #pragma unroll
            for (int qf = 0; qf < 2; ++qf)
                pa[qf] = *(const short8*)&sP[w][qf * 16 + lrow][ks * 32 + lgrp * 8];
            #pragma unroll
            for (int n = 0; n < 4; ++n) {
                const int vr = n * 16 + lrow;
                const short8 vb = *(const short8*)&sKV[buf][8192 + vr * 64 + (((ks * 4 + lgrp) ^ (lrow & 7)) * 8)];
                #pragma unroll
                for (int qf = 0; qf < 2; ++qf)
                    oacc[qf][n] = __builtin_amdgcn_mfma_f32_16x16x32_bf16(pa[qf], vb, oacc[qf][n], 0, 0, 0);
            }
        }

        __syncthreads();   // drains stage vmcnt + guards buf reuse
        buf ^= 1;
    }

    #pragma unroll
    for (int qf = 0; qf < 2; ++qf) {
        const float linv = 1.0f / l[qf];
        float* op = O + ((size_t)h * QL + qb + qf * 16) * DH;
        #pragma unroll
        for (int rr = 0; rr < 4; ++rr) {
            const float lb = __shfl(linv, lgrp * 4 + rr);
            #pragma unroll
            for (int n = 0; n < 4; ++n)
                op[(size_t)(lgrp * 4 + rr) * DH + n * 16 + lrow] = oacc[qf][n][rr] * lb;
        }
    }
}

// ================= fallback (round-1 kernel, proven) =================
#define QT 64
#define KBf 32
#define KSTR 72
#define VSTR 40
#define PSTR 40

__global__ __launch_bounds__(256, 2)
void sdpa_fallback(const float* __restrict__ Q, const float* __restrict__ K,
                   const float* __restrict__ V, float* __restrict__ O)
{
    __shared__ ushort sKh[KBf][KSTR];
    __shared__ ushort sKl[KBf][KSTR];
    __shared__ ushort sVt[DH][VSTR];
    __shared__ ushort sPf[4][16][PSTR];

    const int tid  = threadIdx.x;
    const int lane = tid & 63;
    const int w    = tid >> 6;
    const int h    = blockIdx.y;
    const int q0   = blockIdx.x * QT;
    const int qb   = q0 + w * 16;
    const int lrow = lane & 15;
    const int lgrp = lane >> 4;

    short8 qh[2], ql[2];
    {
        const float* qp = Q + ((size_t)h * QL + (qb + lrow)) * DH;
        #pragma unroll
        for (int dh = 0; dh < 2; ++dh) {
            const int d0 = dh * 32 + lgrp * 8;
            #pragma unroll
            for (int j = 0; j < 8; ++j) {
                float x = qp[d0 + j] * SCALE;
                ushort hb = f2bf(x);
                qh[dh][j] = (short)hb;
                ql[dh][j] = (short)f2bf(x - bf2f(hb));
            }
        }
    }

    f32x4 oacc[4];
    float m_r[4], l_r[4];
    #pragma unroll
    for (int n = 0; n < 4; ++n) { oacc[n][0]=0.f; oacc[n][1]=0.f; oacc[n][2]=0.f; oacc[n][3]=0.f; }
    #pragma unroll
    for (int r = 0; r < 4; ++r) { m_r[r] = -1e30f; l_r[r] = 0.f; }

    const int nkv = min(KVL, PREFIX + q0 + QT);

    for (int kv0 = 0; kv0 < nkv; kv0 += KBf) {
        __syncthreads();
        {
            const int r  = tid >> 3;
            const int d0 = (tid & 7) * 8;
            const float* kp = K + ((size_t)h * KVL + (kv0 + r)) * DH + d0;
            const float* vp = V + ((size_t)h * KVL + (kv0 + r)) * DH + d0;
            short8 vh, vl;
            #pragma unroll
            for (int j = 0; j < 8; ++j) {
                float x = kp[j];
                ushort hb = f2bf(x);
                vh[j] = (short)hb;
                vl[j] = (short)f2bf(x - bf2f(hb));
            }
            *(short8*)&sKh[r][d0] = vh;
            *(short8*)&sKl[r][d0] = vl;
            #pragma unroll
            for (int j = 0; j < 8; ++j)
                sVt[d0 + j][r] = f2bf(vp[j]);
        }
        __syncthreads();

        f32x4 s[2];
        #pragma unroll
        for (int t = 0; t < 2; ++t) { s[t][0]=0.f; s[t][1]=0.f; s[t][2]=0.f; s[t][3]=0.f; }
        #pragma unroll
        for (int t = 0; t < 2; ++t) {
            #pragma unroll
            for (int dh = 0; dh < 2; ++dh) {
                const short8 kh = *(const short8*)&sKh[t*16 + lrow][dh*32 + lgrp*8];
                const short8 kl = *(const short8*)&sKl[t*16 + lrow][dh*32 + lgrp*8];
                s[t] = __builtin_amdgcn_mfma_f32_16x16x32_bf16(qh[dh], kh, s[t], 0, 0, 0);
                s[t] = __builtin_amdgcn_mfma_f32_16x16x32_bf16(qh[dh], kl, s[t], 0, 0, 0);
                s[t] = __builtin_amdgcn_mfma_f32_16x16x32_bf16(ql[dh], kh, s[t], 0, 0, 0);
            }
        }

        if (kv0 + KBf > PREFIX + qb) {
            #pragma unroll
            for (int t = 0; t < 2; ++t)
                #pragma unroll
                for (int r = 0; r < 4; ++r) {
                    const int kv = kv0 + t*16 + lrow;
                    const int q  = qb + lgrp*4 + r;
                    if (kv > PREFIX + q) s[t][r] = -1e30f;
                }
        }

        float tmax[4];
        #pragma unroll
        for (int r = 0; r < 4; ++r) tmax[r] = fmaxf(s[0][r], s[1][r]);
        #pragma unroll
        for (int off = 1; off <= 8; off <<= 1)
            #pragma unroll
            for (int r = 0; r < 4; ++r) tmax[r] = fmaxf(tmax[r], __shfl_xor(tmax[r], off, 64));

        float f[4];
        #pragma unroll
        for (int r = 0; r < 4; ++r) {
            const float mn = fmaxf(m_r[r], tmax[r]);
            f[r] = __expf(m_r[r] - mn);
            m_r[r] = mn;
        }
        #pragma unroll
        for (int t = 0; t < 2; ++t)
            #pragma unroll
            for (int r = 0; r < 4; ++r) s[t][r] = __expf(s[t][r] - m_r[r]);

        float rs[4];
        #pragma unroll
        for (int r = 0; r < 4; ++r) rs[r] = s[0][r] + s[1][r];
        #pragma unroll
        for (int off = 1; off <= 8; off <<= 1)
            #pragma unroll
            for (int r = 0; r < 4; ++r) rs[r] += __shfl_xor(rs[r], off, 64);
        #pragma unroll
        for (int r = 0; r < 4; ++r) l_r[r] = l_r[r] * f[r] + rs[r];
        #pragma unroll
        for (int n = 0; n < 4; ++n)
            #pragma unroll
            for (int r = 0; r < 4; ++r) oacc[n][r] *= f[r];

        #pragma unroll
        for (int t = 0; t < 2; ++t)
            #pragma unroll
            for (int r = 0; r < 4; ++r)
                sPf[w][lgrp*4 + r][t*16 + lrow] = f2bf(s[t][r]);
        asm volatile("s_waitcnt lgkmcnt(0)" ::: "memory");
        __builtin_amdgcn_sched_barrier(0);

        const short8 pa = *(const short8*)&sPf[w][lrow][lgrp*8];
        #pragma unroll
        for (int n = 0; n < 4; ++n) {
            const short8 vb = *(const short8*)&sVt[n*16 + lrow][lgrp*8];
            oacc[n] = __builtin_amdgcn_mfma_f32_16x16x32_bf16(pa, vb, oacc[n], 0, 0, 0);
        }
    }

    float inv[4];
    #pragma unroll
    for (int r = 0; r < 4; ++r) inv[r] = 1.0f / l_r[r];
    float* op = O + ((size_t)h * QL + qb) * DH;
    #pragma unroll
    for (int n = 0; n < 4; ++n)
        #pragma unroll
        for (int r = 0; r < 4; ++r)
            op[(lgrp*4 + r) * DH + n*16 + lrow] = oacc[n][r] * inv[r];
}

extern "C" void kernel_launch(void* const* d_in, const int* in_sizes, int n_in,
                              void* d_out, int out_size, void* d_ws, size_t ws_size,
                              hipStream_t stream) {
    const float* Q = (const float*)d_in[0];
    const float* K = (const float*)d_in[1];
    const float* V = (const float*)d_in[2];
    float* O = (float*)d_out;
    const size_t need = (size_t)NH * NTILES * TILE_US * 2;
    if (ws_size >= need) {
        ushort* wsKV = (ushort*)d_ws;
        hipLaunchKernelGGL(convK, dim3(2048), dim3(256), 0, stream, K, wsKV);
        hipLaunchKernelGGL(convV, dim3(1024), dim3(512), 0, stream, V, wsKV);
        hipLaunchKernelGGL(sdpa_main, dim3(512), dim3(128), 0, stream, Q, wsKV, O);
    } else {
        hipLaunchKernelGGL(sdpa_fallback, dim3(32, 16), dim3(256), 0, stream, Q, K, V, O);
    }
}

// Round 3
// 112.114 us; speedup vs baseline: 2.4145x; 1.4498x over previous
//
#include <hip/hip_runtime.h>
#include <hip/hip_bf16.h>

#define NH 16
#define QL 2048
#define KVL 4096
#define DH 64
#define PREFIX (KVL - QL)
#define KB 64
#define NTILES (KVL / KB)          // 64
#define TILE_US 12288              // ushorts/tile: Kh 4096 | Kl 4096 | Vt 4096
// scale * log2(e): softmax computed in base-2 domain (v_exp_f32 is exp2)
#define SCALE 0.1803368801111243f

typedef __attribute__((ext_vector_type(8))) short short8;
typedef __attribute__((ext_vector_type(4))) float f32x4;
typedef unsigned int u32;
typedef __attribute__((ext_vector_type(2))) u32 u32x2;

static __device__ __forceinline__ ushort f2bf(float x) {
    union { float f; u32 u; } v; v.f = x;
    u32 r = v.u + 0x7fffu + ((v.u >> 16) & 1u);   // RTNE
    return (ushort)(r >> 16);
}
static __device__ __forceinline__ float bf2f(ushort h) {
    union { u32 u; float f; } v; v.u = ((u32)h) << 16;
    return v.f;
}
static __device__ __forceinline__ float exp2_fast(float x) {
    float r; asm("v_exp_f32 %0, %1" : "=v"(r) : "v"(x)); return r;
}
static __device__ __forceinline__ u32 cvtpk_bf16(float lo, float hi) {
    u32 r; asm("v_cvt_pk_bf16_f32 %0, %1, %2" : "=v"(r) : "v"(lo), "v"(hi)); return r;
}
static __device__ __forceinline__ void gload_lds16(const ushort* g, ushort* l) {
    __builtin_amdgcn_global_load_lds(
        (const __attribute__((address_space(1))) u32*)g,
        (__attribute__((address_space(3))) u32*)l, 16, 0, 0);
}

// ---- precompute: K -> Kh/Kl bf16, tile-blocked [h][tile][kv 64][chunk^swz] ----
__global__ void convK(const float* __restrict__ K, ushort* __restrict__ wsKV) {
    const int gid = blockIdx.x * 256 + threadIdx.x;   // 16*4096*8 = 524288
    const int c8 = gid & 7;
    const int kv = (gid >> 3) & (KVL - 1);
    const int h  = gid >> 15;
    const float* src = K + ((size_t)h * KVL + kv) * DH + c8 * 8;
    const float4 a = *(const float4*)src;
    const float4 b = *(const float4*)(src + 4);
    const float v[8] = {a.x, a.y, a.z, a.w, b.x, b.y, b.z, b.w};
    short8 hi, lo;
    #pragma unroll
    for (int j = 0; j < 8; ++j) {
        const ushort hb = f2bf(v[j]);
        hi[j] = (short)hb;
        lo[j] = (short)f2bf(v[j] - bf2f(hb));
    }
    const int tile = kv >> 6, r = kv & 63;
    ushort* dst = wsKV + (size_t)(h * NTILES + tile) * TILE_US;
    const int off = r * 64 + ((c8 ^ (r & 7)) * 8);
    *(short8*)(dst + off) = hi;
    *(short8*)(dst + 4096 + off) = lo;
}

// ---- precompute: V -> Vt bf16 [h][tile][d 64][kvchunk^swz] (transposed) ----
__global__ void convV(const float* __restrict__ V, ushort* __restrict__ wsKV) {
    const int bx = blockIdx.x;            // h*64 + tile
    const int h = bx >> 6, tile = bx & 63;
    const int d  = threadIdx.x & 63;
    const int k8 = threadIdx.x >> 6;      // 0..7
    const float* src = V + ((size_t)h * KVL + tile * 64 + k8 * 8) * DH + d;
    short8 o;
    #pragma unroll
    for (int j = 0; j < 8; ++j) o[j] = (short)f2bf(src[j * DH]);
    ushort* dst = wsKV + (size_t)(h * NTILES + tile) * TILE_US + 8192
                + d * 64 + ((k8 ^ (d & 7)) * 8);
    *(short8*)dst = o;
}

// ---- main: 4 waves/block, 16 q rows/wave, KB=64, dbuf global_load_lds ----
__global__ __launch_bounds__(256, 2)
void sdpa_main(const float* __restrict__ Q, const ushort* __restrict__ wsKV,
               float* __restrict__ O)
{
    __shared__ ushort sKV[2][TILE_US];    // [Kh 8KB | Kl 8KB | Vt 8KB] per buf
    __shared__ ushort sP[4][16][72];      // per-wave P[q][kv], 144B rows

    const int tid  = threadIdx.x;
    const int lane = tid & 63;
    const int w    = tid >> 6;
    const int lrow = lane & 15;
    const int lgrp = lane >> 4;

    // XCD-aware: 2 heads/XCD (K/V ws L2-resident); long+short q-block pairing
    const int bid  = blockIdx.x;
    const int xcd  = bid & 7;
    const int slot = bid >> 3;            // 0..63
    const int h    = xcd * 2 + (slot >> 5);
    const int s    = slot & 31;
    const int qx   = (s & 1) ? (31 - (s >> 1)) : (s >> 1);
    const int q0   = qx * 64;
    const int qb   = q0 + w * 16;         // this wave's 16 q rows
    const int qme  = qb + lrow;           // this lane's q row

    // Q fragments (hi/lo split, pre-scaled by scale*log2e)
    short8 qh[2], ql[2];
    {
        const float* qp = Q + ((size_t)h * QL + qme) * DH;
        #pragma unroll
        for (int dh = 0; dh < 2; ++dh) {
            #pragma unroll
            for (int j = 0; j < 8; ++j) {
                const float x = qp[dh * 32 + lgrp * 8 + j] * SCALE;
                const ushort hb = f2bf(x);
                qh[dh][j] = (short)hb;
                ql[dh][j] = (short)f2bf(x - bf2f(hb));
            }
        }
    }

    // O^T accumulator: lane owns q=qme; oaccT[n][r] = O[qme][n*16 + lgrp*4 + r]
    f32x4 oaccT[4];
    #pragma unroll
    for (int n = 0; n < 4; ++n)
        #pragma unroll
        for (int r = 0; r < 4; ++r) oaccT[n][r] = 0.f;
    float m = -1e30f, l = 0.f;

    const int nt = (PREFIX + q0 + 64) / KB;
    const ushort* hbase = wsKV + (size_t)h * NTILES * TILE_US;

    // prologue: stage tile 0
    #pragma unroll
    for (int k = 0; k < 6; ++k) {
        const int off = (k * 256 + tid) * 8;
        gload_lds16(hbase + off, &sKV[0][off]);
    }
    __syncthreads();

    int buf = 0;
    for (int it = 0; it < nt; ++it) {
        if (it + 1 < nt) {
            const ushort* src = hbase + (size_t)(it + 1) * TILE_US;
            #pragma unroll
            for (int k = 0; k < 6; ++k) {
                const int off = (k * 256 + tid) * 8;
                gload_lds16(src + off, &sKV[buf ^ 1][off]);
            }
        }

        // ---- QK^T swapped: sT[t][r] = S[kv=16t+lgrp*4+r][q=qme] (log2 domain) ----
        f32x4 sT[4];
        #pragma unroll
        for (int t = 0; t < 4; ++t)
            #pragma unroll
            for (int r = 0; r < 4; ++r) sT[t][r] = 0.f;

        __builtin_amdgcn_s_setprio(1);
        #pragma unroll
        for (int t = 0; t < 4; ++t) {
            const int r = t * 16 + lrow;
            #pragma unroll
            for (int dh = 0; dh < 2; ++dh) {
                const int co = r * 64 + (((dh * 4 + lgrp) ^ (lrow & 7)) * 8);
                const short8 kh = *(const short8*)&sKV[buf][co];
                const short8 kl = *(const short8*)&sKV[buf][4096 + co];
                sT[t] = __builtin_amdgcn_mfma_f32_16x16x32_bf16(kh, qh[dh], sT[t], 0, 0, 0);
                sT[t] = __builtin_amdgcn_mfma_f32_16x16x32_bf16(kl, qh[dh], sT[t], 0, 0, 0);
                sT[t] = __builtin_amdgcn_mfma_f32_16x16x32_bf16(kh, ql[dh], sT[t], 0, 0, 0);
            }
        }
        __builtin_amdgcn_s_setprio(0);

        const int kv0 = it * KB;
        if (kv0 + KB > PREFIX + qb) {           // wave-uniform boundary check
            const int kvlim = PREFIX + qme - kv0;
            #pragma unroll
            for (int t = 0; t < 4; ++t)
                #pragma unroll
                for (int r = 0; r < 4; ++r)
                    if (t * 16 + lgrp * 4 + r > kvlim) sT[t][r] = -1e30f;
        }

        // ---- lane-local online softmax (q = qme), base-2 ----
        float mx;
        {
            float a0 = fmaxf(fmaxf(sT[0][0], sT[0][1]), fmaxf(sT[0][2], sT[0][3]));
            float a1 = fmaxf(fmaxf(sT[1][0], sT[1][1]), fmaxf(sT[1][2], sT[1][3]));
            float a2 = fmaxf(fmaxf(sT[2][0], sT[2][1]), fmaxf(sT[2][2], sT[2][3]));
            float a3 = fmaxf(fmaxf(sT[3][0], sT[3][1]), fmaxf(sT[3][2], sT[3][3]));
            mx = fmaxf(fmaxf(a0, a1), fmaxf(a2, a3));
        }
        mx = fmaxf(mx, __shfl_xor(mx, 16));
        mx = fmaxf(mx, __shfl_xor(mx, 32));
        const float mn  = fmaxf(m, mx);
        const float fsc = exp2_fast(m - mn);
        m = mn;

        float rs = 0.f;
        #pragma unroll
        for (int t = 0; t < 4; ++t)
            #pragma unroll
            for (int r = 0; r < 4; ++r) {
                const float p = exp2_fast(sT[t][r] - mn);
                sT[t][r] = p;
                rs += p;
            }
        rs += __shfl_xor(rs, 16);
        rs += __shfl_xor(rs, 32);
        l = l * fsc + rs;

        #pragma unroll
        for (int n = 0; n < 4; ++n)
            #pragma unroll
            for (int r = 0; r < 4; ++r) oaccT[n][r] *= fsc;

        // ---- P -> bf16 pairs -> wave-private LDS [q][kv] ----
        #pragma unroll
        for (int t = 0; t < 4; ++t) {
            u32x2 pw;
            pw[0] = cvtpk_bf16(sT[t][0], sT[t][1]);
            pw[1] = cvtpk_bf16(sT[t][2], sT[t][3]);
            *(u32x2*)&sP[w][lrow][t * 16 + lgrp * 4] = pw;
        }
        asm volatile("s_waitcnt lgkmcnt(0)" ::: "memory");
        __builtin_amdgcn_sched_barrier(0);

        // ---- PV transposed: oaccT[n] += V^T-tile * P^T (O^T layout) ----
        __builtin_amdgcn_s_setprio(1);
        #pragma unroll
        for (int ks = 0; ks < 2; ++ks) {
            const short8 pa = *(const short8*)&sP[w][lrow][ks * 32 + lgrp * 8];
            #pragma unroll
            for (int n = 0; n < 4; ++n) {
                const int vr = n * 16 + lrow;
                const short8 vb = *(const short8*)&sKV[buf][8192 + vr * 64 + (((ks * 4 + lgrp) ^ (vr & 7)) * 8)];
                oaccT[n] = __builtin_amdgcn_mfma_f32_16x16x32_bf16(vb, pa, oaccT[n], 0, 0, 0);
            }
        }
        __builtin_amdgcn_s_setprio(0);

        __syncthreads();   // drains stage vmcnt + guards buf reuse
        buf ^= 1;
    }

    // ---- epilogue: lane-local divide, f32x4 stores ----
    const float linv = 1.0f / l;
    float* op = O + ((size_t)h * QL + qme) * DH;
    #pragma unroll
    for (int n = 0; n < 4; ++n) {
        f32x4 o;
        #pragma unroll
        for (int r = 0; r < 4; ++r) o[r] = oaccT[n][r] * linv;
        *(f32x4*)(op + n * 16 + lgrp * 4) = o;
    }
}

// ================= fallback (round-1 kernel, proven, no ws needed) =================
#define QT 64
#define KBf 32
#define KSTR 72
#define VSTR 40
#define PSTR 40
#define SCALE_E 0.125f

__global__ __launch_bounds__(256, 2)
void sdpa_fallback(const float* __restrict__ Q, const float* __restrict__ K,
                   const float* __restrict__ V, float* __restrict__ O)
{
    __shared__ ushort sKh[KBf][KSTR];
    __shared__ ushort sKl[KBf][KSTR];
    __shared__ ushort sVt[DH][VSTR];
    __shared__ ushort sPf[4][16][PSTR];

    const int tid  = threadIdx.x;
    const int lane = tid & 63;
    const int w    = tid >> 6;
    const int h    = blockIdx.y;
    const int q0   = blockIdx.x * QT;
    const int qb   = q0 + w * 16;
    const int lrow = lane & 15;
    const int lgrp = lane >> 4;

    short8 qh[2], ql[2];
    {
        const float* qp = Q + ((size_t)h * QL + (qb + lrow)) * DH;
        #pragma unroll
        for (int dh = 0; dh < 2; ++dh) {
            const int d0 = dh * 32 + lgrp * 8;
            #pragma unroll
            for (int j = 0; j < 8; ++j) {
                float x = qp[d0 + j] * SCALE_E;
                ushort hb = f2bf(x);
                qh[dh][j] = (short)hb;
                ql[dh][j] = (short)f2bf(x - bf2f(hb));
            }
        }
    }

    f32x4 oacc[4];
    float m_r[4], l_r[4];
    #pragma unroll
    for (int n = 0; n < 4; ++n) { oacc[n][0]=0.f; oacc[n][1]=0.f; oacc[n][2]=0.f; oacc[n][3]=0.f; }
    #pragma unroll
    for (int r = 0; r < 4; ++r) { m_r[r] = -1e30f; l_r[r] = 0.f; }

    const int nkv = min(KVL, PREFIX + q0 + QT);

    for (int kv0 = 0; kv0 < nkv; kv0 += KBf) {
        __syncthreads();
        {
            const int r  = tid >> 3;
            const int d0 = (tid & 7) * 8;
            const float* kp = K + ((size_t)h * KVL + (kv0 + r)) * DH + d0;
            const float* vp = V + ((size_t)h * KVL + (kv0 + r)) * DH + d0;
            short8 vh, vl;
            #pragma unroll
            for (int j = 0; j < 8; ++j) {
                float x = kp[j];
                ushort hb = f2bf(x);
                vh[j] = (short)hb;
                vl[j] = (short)f2bf(x - bf2f(hb));
            }
            *(short8*)&sKh[r][d0] = vh;
            *(short8*)&sKl[r][d0] = vl;
            #pragma unroll
            for (int j = 0; j < 8; ++j)
                sVt[d0 + j][r] = f2bf(vp[j]);
        }
        __syncthreads();

        f32x4 s[2];
        #pragma unroll
        for (int t = 0; t < 2; ++t) { s[t][0]=0.f; s[t][1]=0.f; s[t][2]=0.f; s[t][3]=0.f; }
        #pragma unroll
        for (int t = 0; t < 2; ++t) {
            #pragma unroll
            for (int dh = 0; dh < 2; ++dh) {
                const short8 kh = *(const short8*)&sKh[t*16 + lrow][dh*32 + lgrp*8];
                const short8 kl = *(const short8*)&sKl[t*16 + lrow][dh*32 + lgrp*8];
                s[t] = __builtin_amdgcn_mfma_f32_16x16x32_bf16(qh[dh], kh, s[t], 0, 0, 0);
                s[t] = __builtin_amdgcn_mfma_f32_16x16x32_bf16(qh[dh], kl, s[t], 0, 0, 0);
                s[t] = __builtin_amdgcn_mfma_f32_16x16x32_bf16(ql[dh], kh, s[t], 0, 0, 0);
            }
        }

        if (kv0 + KBf > PREFIX + qb) {
            #pragma unroll
            for (int t = 0; t < 2; ++t)
                #pragma unroll
                for (int r = 0; r < 4; ++r) {
                    const int kv = kv0 + t*16 + lrow;
                    const int q  = qb + lgrp*4 + r;
                    if (kv > PREFIX + q) s[t][r] = -1e30f;
                }
        }

        float tmax[4];
        #pragma unroll
        for (int r = 0; r < 4; ++r) tmax[r] = fmaxf(s[0][r], s[1][r]);
        #pragma unroll
        for (int off = 1; off <= 8; off <<= 1)
            #pragma unroll
            for (int r = 0; r < 4; ++r) tmax[r] = fmaxf(tmax[r], __shfl_xor(tmax[r], off, 64));

        float f[4];
        #pragma unroll
        for (int r = 0; r < 4; ++r) {
            const float mn = fmaxf(m_r[r], tmax[r]);
            f[r] = __expf(m_r[r] - mn);
            m_r[r] = mn;
        }
        #pragma unroll
        for (int t = 0; t < 2; ++t)
            #pragma unroll
            for (int r = 0; r < 4; ++r) s[t][r] = __expf(s[t][r] - m_r[r]);

        float rs[4];
        #pragma unroll
        for (int r = 0; r < 4; ++r) rs[r] = s[0][r] + s[1][r];
        #pragma unroll
        for (int off = 1; off <= 8; off <<= 1)
            #pragma unroll
            for (int r = 0; r < 4; ++r) rs[r] += __shfl_xor(rs[r], off, 64);
        #pragma unroll
        for (int r = 0; r < 4; ++r) l_r[r] = l_r[r] * f[r] + rs[r];
        #pragma unroll
        for (int n = 0; n < 4; ++n)
            #pragma unroll
            for (int r = 0; r < 4; ++r) oacc[n][r] *= f[r];

        #pragma unroll
        for (int t = 0; t < 2; ++t)
            #pragma unroll
            for (int r = 0; r < 4; ++r)
                sPf[w][lgrp*4 + r][t*16 + lrow] = f2bf(s[t][r]);
        asm volatile("s_waitcnt lgkmcnt(0)" ::: "memory");
        __builtin_amdgcn_sched_barrier(0);

        const short8 pa = *(const short8*)&sPf[w][lrow][lgrp*8];
        #pragma unroll
        for (int n = 0; n < 4; ++n) {
            const short8 vb = *(const short8*)&sVt[n*16 + lrow][lgrp*8];
            oacc[n] = __builtin_amdgcn_mfma_f32_16x16x32_bf16(pa, vb, oacc[n], 0, 0, 0);
        }
    }

    float inv[4];
    #pragma unroll
    for (int r = 0; r < 4; ++r) inv[r] = 1.0f / l_r[r];
    float* op = O + ((size_t)h * QL + qb) * DH;
    #pragma unroll
    for (int n = 0; n < 4; ++n)
        #pragma unroll
        for (int r = 0; r < 4; ++r)
            op[(lgrp*4 + r) * DH + n*16 + lrow] = oacc[n][r] * inv[r];
}

extern "C" void kernel_launch(void* const* d_in, const int* in_sizes, int n_in,
                              void* d_out, int out_size, void* d_ws, size_t ws_size,
                              hipStream_t stream) {
    const float* Q = (const float*)d_in[0];
    const float* K = (const float*)d_in[1];
    const float* V = (const float*)d_in[2];
    float* O = (float*)d_out;
    const size_t need = (size_t)NH * NTILES * TILE_US * 2;
    if (ws_size >= need) {
        ushort* wsKV = (ushort*)d_ws;
        hipLaunchKernelGGL(convK, dim3(2048), dim3(256), 0, stream, K, wsKV);
        hipLaunchKernelGGL(convV, dim3(1024), dim3(512), 0, stream, V, wsKV);
        hipLaunchKernelGGL(sdpa_main, dim3(512), dim3(256), 0, stream, Q, wsKV, O);
    } else {
        hipLaunchKernelGGL(sdpa_fallback, dim3(32, 16), dim3(256), 0, stream, Q, K, V, O);
    }
}

// Round 4
// 102.293 us; speedup vs baseline: 2.6463x; 1.0960x over previous
//
#include <hip/hip_runtime.h>
#include <hip/hip_bf16.h>

#define NH 16
#define QL 2048
#define KVL 4096
#define DH 64
#define PREFIX (KVL - QL)
#define NTILES (KVL / 64)          // 64 kv-tiles of 64
#define TILE_US 12288              // ushorts/tile: Kh 4096 | Kl 4096 | Vt 4096
// scale * log2(e): softmax in base-2 domain (v_exp_f32 is exp2)
#define SCALE 0.1803368801111243f

typedef __attribute__((ext_vector_type(8))) short short8;
typedef __attribute__((ext_vector_type(4))) float f32x4;
typedef __attribute__((ext_vector_type(16))) float f32x16;
typedef unsigned int u32;
typedef __attribute__((ext_vector_type(2))) u32 u32x2;

static __device__ __forceinline__ ushort f2bf(float x) {
    union { float f; u32 u; } v; v.f = x;
    u32 r = v.u + 0x7fffu + ((v.u >> 16) & 1u);   // RTNE
    return (ushort)(r >> 16);
}
static __device__ __forceinline__ float bf2f(ushort h) {
    union { u32 u; float f; } v; v.u = ((u32)h) << 16;
    return v.f;
}
static __device__ __forceinline__ float exp2_fast(float x) {
    float r; asm("v_exp_f32 %0, %1" : "=v"(r) : "v"(x)); return r;
}
static __device__ __forceinline__ u32 cvtpk_bf16(float lo, float hi) {
    u32 r; asm("v_cvt_pk_bf16_f32 %0, %1, %2" : "=v"(r) : "v"(lo), "v"(hi)); return r;
}
static __device__ __forceinline__ void gload_lds16(const ushort* g, ushort* l) {
    __builtin_amdgcn_global_load_lds(
        (const __attribute__((address_space(1))) u32*)g,
        (__attribute__((address_space(3))) u32*)l, 16, 0, 0);
}
#define MFMA32(a, b, c) __builtin_amdgcn_mfma_f32_32x32x16_bf16(a, b, c, 0, 0, 0)

// ---- precompute: K -> Kh/Kl bf16, tile-blocked [h][tile][kv 64][chunk^swz] ----
__global__ void convK(const float* __restrict__ K, ushort* __restrict__ wsKV) {
    const int gid = blockIdx.x * 256 + threadIdx.x;   // 16*4096*8 = 524288
    const int c8 = gid & 7;
    const int kv = (gid >> 3) & (KVL - 1);
    const int h  = gid >> 15;
    const float* src = K + ((size_t)h * KVL + kv) * DH + c8 * 8;
    const float4 a = *(const float4*)src;
    const float4 b = *(const float4*)(src + 4);
    const float v[8] = {a.x, a.y, a.z, a.w, b.x, b.y, b.z, b.w};
    short8 hi, lo;
    #pragma unroll
    for (int j = 0; j < 8; ++j) {
        const ushort hb = f2bf(v[j]);
        hi[j] = (short)hb;
        lo[j] = (short)f2bf(v[j] - bf2f(hb));
    }
    const int tile = kv >> 6, r = kv & 63;
    ushort* dst = wsKV + (size_t)(h * NTILES + tile) * TILE_US;
    const int off = r * 64 + ((c8 ^ (r & 7)) * 8);
    *(short8*)(dst + off) = hi;
    *(short8*)(dst + 4096 + off) = lo;
}

// ---- precompute: V -> Vt bf16 [h][tile][d 64][kvchunk^swz] (transposed) ----
__global__ void convV(const float* __restrict__ V, ushort* __restrict__ wsKV) {
    const int bx = blockIdx.x;            // h*64 + tile
    const int h = bx >> 6, tile = bx & 63;
    const int d  = threadIdx.x & 63;
    const int k8 = threadIdx.x >> 6;      // 0..7
    const float* src = V + ((size_t)h * KVL + tile * 64 + k8 * 8) * DH + d;
    short8 o;
    #pragma unroll
    for (int j = 0; j < 8; ++j) o[j] = (short)f2bf(src[j * DH]);
    ushort* dst = wsKV + (size_t)(h * NTILES + tile) * TILE_US + 8192
                + d * 64 + ((k8 ^ (d & 7)) * 8);
    *(short8*)dst = o;
}

// ==== main: 2 waves/block, 32 q/wave (32x32x16 MFMA), single-buffer LDS, ====
// ==== fused QK(i)+PV(i-1) cluster, kv-split NS with partial (O,m,l) output ====
template<int NS>
__global__ __launch_bounds__(128, 2)
void sdpa_main(const float* __restrict__ Q, const ushort* __restrict__ wsKV,
               float* __restrict__ O, float* __restrict__ part)
{
    __shared__ ushort sKh[4096];
    __shared__ ushort sKl[4096];
    __shared__ ushort sVt[4096];
    __shared__ ushort sP[2][32][72];

    const int tid  = threadIdx.x;
    const int lane = tid & 63;
    const int w    = tid >> 6;
    const int lq   = lane & 31;           // this lane's q (within wave) / row idx
    const int hi   = lane >> 5;

    // mapping: 2 heads/XCD; slot -> (hsub, qx, sp)
    const int bid  = blockIdx.x;
    const int xcd  = bid & 7;
    const int slot = bid >> 3;            // 0 .. 64*NS-1
    const int h    = xcd * 2 + slot / (32 * NS);
    const int rem  = slot % (32 * NS);
    const int qx   = rem / NS;
    const int sp   = rem % NS;
    const int q0   = qx * 64;
    const int qb   = q0 + w * 32;

    const int ntt = 33 + qx;              // total kv tiles for this q-block
    const int t0  = (ntt * sp) / NS;
    const int t1  = (ntt * (sp + 1)) / NS;

    // ---- Q B-fragments (hi/lo split, pre-scaled by scale*log2e) ----
    short8 qh[4], ql[4];
    {
        const float* qp = Q + ((size_t)h * QL + qb + lq) * DH;
        #pragma unroll
        for (int ks = 0; ks < 4; ++ks) {
            const int d0 = ks * 16 + hi * 8;
            const float4 a = *(const float4*)(qp + d0);
            const float4 b = *(const float4*)(qp + d0 + 4);
            const float v[8] = {a.x, a.y, a.z, a.w, b.x, b.y, b.z, b.w};
            #pragma unroll
            for (int j = 0; j < 8; ++j) {
                const float x = v[j] * SCALE;
                const ushort hb = f2bf(x);
                qh[ks][j] = (short)hb;
                ql[ks][j] = (short)f2bf(x - bf2f(hb));
            }
        }
    }

    // O^T accumulator: oacc[dt][r] = O[qb+lq][32dt + (r&3)+8(r>>2)+4hi]
    f32x16 oacc[2];
    #pragma unroll
    for (int dt = 0; dt < 2; ++dt)
        #pragma unroll
        for (int r = 0; r < 16; ++r) oacc[dt][r] = 0.f;
    float m = -1e30f, lsum = 0.f;

    const ushort* hbase = wsKV + (size_t)h * NTILES * TILE_US;

    // prologue: stage K(t0)
    {
        const ushort* src = hbase + (size_t)t0 * TILE_US;
        #pragma unroll
        for (int k = 0; k < 4; ++k) {
            const int off = (k * 128 + tid) * 8;
            gload_lds16(src + off, &sKh[off]);
            gload_lds16(src + 4096 + off, &sKl[off]);
        }
    }
    __syncthreads();

    for (int it = t0; it < t1; ++it) {
        // ---- MFMA cluster: QK(it) + PV(it-1) ----
        f32x16 sT[2];
        #pragma unroll
        for (int t = 0; t < 2; ++t)
            #pragma unroll
            for (int r = 0; r < 16; ++r) sT[t][r] = 0.f;

        __builtin_amdgcn_s_setprio(1);
        #pragma unroll
        for (int t = 0; t < 2; ++t) {
            const int row = t * 32 + lq;
            #pragma unroll
            for (int ks = 0; ks < 4; ++ks) {
                const int co = row * 64 + (((2 * ks + hi) ^ (lq & 7)) * 8);
                const short8 kh = *(const short8*)&sKh[co];
                const short8 kl = *(const short8*)&sKl[co];
                sT[t] = MFMA32(kh, qh[ks], sT[t]);
                sT[t] = MFMA32(kl, qh[ks], sT[t]);
                sT[t] = MFMA32(kh, ql[ks], sT[t]);
            }
        }
        if (it > t0) {
            #pragma unroll
            for (int ks = 0; ks < 4; ++ks) {
                const short8 pb = *(const short8*)&sP[w][lq][ks * 16 + hi * 8];
                #pragma unroll
                for (int dt = 0; dt < 2; ++dt) {
                    const int co = (dt * 32 + lq) * 64 + (((2 * ks + hi) ^ (lq & 7)) * 8);
                    const short8 vb = *(const short8*)&sVt[co];
                    oacc[dt] = MFMA32(vb, pb, oacc[dt]);
                }
            }
        }
        __builtin_amdgcn_s_setprio(0);
        __syncthreads();                 // barA: all waves done reading sK*/sVt

        // ---- stage K(it+1) and V(it) in place ----
        if (it + 1 < t1) {
            const ushort* src = hbase + (size_t)(it + 1) * TILE_US;
            #pragma unroll
            for (int k = 0; k < 4; ++k) {
                const int off = (k * 128 + tid) * 8;
                gload_lds16(src + off, &sKh[off]);
                gload_lds16(src + 4096 + off, &sKl[off]);
            }
        }
        {
            const ushort* src = hbase + (size_t)it * TILE_US + 8192;
            #pragma unroll
            for (int k = 0; k < 4; ++k) {
                const int off = (k * 128 + tid) * 8;
                gload_lds16(src + off, &sVt[off]);
            }
        }

        // ---- softmax(it), base-2, lane-local (q = qb+lq) ----
        const int kv0 = it * 64;
        if (kv0 + 64 > PREFIX + qb) {
            const int kvlim = PREFIX + qb + lq - kv0;
            #pragma unroll
            for (int t = 0; t < 2; ++t)
                #pragma unroll
                for (int r = 0; r < 16; ++r) {
                    const int kv = t * 32 + (r & 3) + 8 * (r >> 2) + 4 * hi;
                    if (kv > kvlim) sT[t][r] = -1e30f;
                }
        }
        float mx = sT[0][0];
        #pragma unroll
        for (int t = 0; t < 2; ++t)
            #pragma unroll
            for (int r = 0; r < 16; ++r) mx = fmaxf(mx, sT[t][r]);
        mx = fmaxf(mx, __shfl_xor(mx, 32));
        const float mn  = fmaxf(m, mx);
        const float fsc = exp2_fast(m - mn);
        m = mn;
        float rs = 0.f;
        #pragma unroll
        for (int t = 0; t < 2; ++t)
            #pragma unroll
            for (int r = 0; r < 16; ++r) {
                const float p = exp2_fast(sT[t][r] - mn);
                sT[t][r] = p;
                rs += p;
            }
        lsum = lsum * fsc + rs;          // per-lane partial; reduced at epilogue
        #pragma unroll
        for (int dt = 0; dt < 2; ++dt)
            #pragma unroll
            for (int r = 0; r < 16; ++r) oacc[dt][r] *= fsc;

        // ---- P -> bf16 -> wave-private sP[q][kv] ----
        #pragma unroll
        for (int t = 0; t < 2; ++t)
            #pragma unroll
            for (int q4 = 0; q4 < 4; ++q4) {
                u32x2 pw;
                pw[0] = cvtpk_bf16(sT[t][q4 * 4 + 0], sT[t][q4 * 4 + 1]);
                pw[1] = cvtpk_bf16(sT[t][q4 * 4 + 2], sT[t][q4 * 4 + 3]);
                *(u32x2*)&sP[w][lq][t * 32 + q4 * 8 + hi * 4] = pw;
            }

        __syncthreads();                 // barB: drain staging vmcnt + lgkm
    }

    // ---- tail: PV(t1-1) ----
    __builtin_amdgcn_s_setprio(1);
    #pragma unroll
    for (int ks = 0; ks < 4; ++ks) {
        const short8 pb = *(const short8*)&sP[w][lq][ks * 16 + hi * 8];
        #pragma unroll
        for (int dt = 0; dt < 2; ++dt) {
            const int co = (dt * 32 + lq) * 64 + (((2 * ks + hi) ^ (lq & 7)) * 8);
            const short8 vb = *(const short8*)&sVt[co];
            oacc[dt] = MFMA32(vb, pb, oacc[dt]);
        }
    }
    __builtin_amdgcn_s_setprio(0);

    // ---- epilogue ----
    const float ltot = lsum + __shfl_xor(lsum, 32);
    if (NS > 1) {
        float* pr = part + ((size_t)(sp * NH + h) * QL + qb + lq) * 68;
        #pragma unroll
        for (int dt = 0; dt < 2; ++dt)
            #pragma unroll
            for (int q4 = 0; q4 < 4; ++q4) {
                f32x4 o;
                #pragma unroll
                for (int j = 0; j < 4; ++j) o[j] = oacc[dt][q4 * 4 + j];
                *(f32x4*)(pr + dt * 32 + q4 * 8 + hi * 4) = o;
            }
        if (hi == 0) { pr[64] = m; pr[65] = ltot; }
    } else {
        const float linv = 1.0f / ltot;
        float* op = O + ((size_t)h * QL + qb + lq) * DH;
        #pragma unroll
        for (int dt = 0; dt < 2; ++dt)
            #pragma unroll
            for (int q4 = 0; q4 < 4; ++q4) {
                f32x4 o;
                #pragma unroll
                for (int j = 0; j < 4; ++j) o[j] = oacc[dt][q4 * 4 + j] * linv;
                *(f32x4*)(op + dt * 32 + q4 * 8 + hi * 4) = o;
            }
    }
}

// ---- combine NS partials: O = sum_j 2^(m_j-M) O_j / sum_j 2^(m_j-M) l_j ----
template<int NS>
__global__ void combine(const float* __restrict__ part, float* __restrict__ O) {
    const int row = blockIdx.x * 4 + (threadIdx.x >> 6);  // h*QL + q
    const int d   = threadIdx.x & 63;
    float mj[NS], lj[NS];
    float M = -1e30f;
    #pragma unroll
    for (int j = 0; j < NS; ++j) {
        const float* p = part + ((size_t)j * NH * QL + row) * 68;
        mj[j] = p[64]; lj[j] = p[65];
        M = fmaxf(M, mj[j]);
    }
    float num = 0.f, den = 0.f;
    #pragma unroll
    for (int j = 0; j < NS; ++j) {
        const float* p = part + ((size_t)j * NH * QL + row) * 68;
        const float wj = exp2f(mj[j] - M);
        num += wj * p[d];
        den += wj * lj[j];
    }
    O[(size_t)row * DH + d] = num / den;
}

// ================= fallback (round-1 kernel, proven, no ws needed) =================
#define QT 64
#define KBf 32
#define KSTR 72
#define VSTR 40
#define PSTR 40
#define SCALE_E 0.125f

__global__ __launch_bounds__(256, 2)
void sdpa_fallback(const float* __restrict__ Q, const float* __restrict__ K,
                   const float* __restrict__ V, float* __restrict__ O)
{
    __shared__ ushort sKh[KBf][KSTR];
    __shared__ ushort sKl[KBf][KSTR];
    __shared__ ushort sVt[DH][VSTR];
    __shared__ ushort sPf[4][16][PSTR];

    const int tid  = threadIdx.x;
    const int lane = tid & 63;
    const int w    = tid >> 6;
    const int h    = blockIdx.y;
    const int q0   = blockIdx.x * QT;
    const int qb   = q0 + w * 16;
    const int lrow = lane & 15;
    const int lgrp = lane >> 4;

    short8 qh[2], ql[2];
    {
        const float* qp = Q + ((size_t)h * QL + (qb + lrow)) * DH;
        #pragma unroll
        for (int dh = 0; dh < 2; ++dh) {
            const int d0 = dh * 32 + lgrp * 8;
            #pragma unroll
            for (int j = 0; j < 8; ++j) {
                float x = qp[d0 + j] * SCALE_E;
                ushort hb = f2bf(x);
                qh[dh][j] = (short)hb;
                ql[dh][j] = (short)f2bf(x - bf2f(hb));
            }
        }
    }

    f32x4 oacc[4];
    float m_r[4], l_r[4];
    #pragma unroll
    for (int n = 0; n < 4; ++n) { oacc[n][0]=0.f; oacc[n][1]=0.f; oacc[n][2]=0.f; oacc[n][3]=0.f; }
    #pragma unroll
    for (int r = 0; r < 4; ++r) { m_r[r] = -1e30f; l_r[r] = 0.f; }

    const int nkv = min(KVL, PREFIX + q0 + QT);

    for (int kv0 = 0; kv0 < nkv; kv0 += KBf) {
        __syncthreads();
        {
            const int r  = tid >> 3;
            const int d0 = (tid & 7) * 8;
            const float* kp = K + ((size_t)h * KVL + (kv0 + r)) * DH + d0;
            const float* vp = V + ((size_t)h * KVL + (kv0 + r)) * DH + d0;
            short8 vh, vl;
            #pragma unroll
            for (int j = 0; j < 8; ++j) {
                float x = kp[j];
                ushort hb = f2bf(x);
                vh[j] = (short)hb;
                vl[j] = (short)f2bf(x - bf2f(hb));
            }
            *(short8*)&sKh[r][d0] = vh;
            *(short8*)&sKl[r][d0] = vl;
            #pragma unroll
            for (int j = 0; j < 8; ++j)
                sVt[d0 + j][r] = f2bf(vp[j]);
        }
        __syncthreads();

        f32x4 s[2];
        #pragma unroll
        for (int t = 0; t < 2; ++t) { s[t][0]=0.f; s[t][1]=0.f; s[t][2]=0.f; s[t][3]=0.f; }
        #pragma unroll
        for (int t = 0; t < 2; ++t) {
            #pragma unroll
            for (int dh = 0; dh < 2; ++dh) {
                const short8 kh = *(const short8*)&sKh[t*16 + lrow][dh*32 + lgrp*8];
                const short8 kl = *(const short8*)&sKl[t*16 + lrow][dh*32 + lgrp*8];
                s[t] = __builtin_amdgcn_mfma_f32_16x16x32_bf16(qh[dh], kh, s[t], 0, 0, 0);
                s[t] = __builtin_amdgcn_mfma_f32_16x16x32_bf16(qh[dh], kl, s[t], 0, 0, 0);
                s[t] = __builtin_amdgcn_mfma_f32_16x16x32_bf16(ql[dh], kh, s[t], 0, 0, 0);
            }
        }

        if (kv0 + KBf > PREFIX + qb) {
            #pragma unroll
            for (int t = 0; t < 2; ++t)
                #pragma unroll
                for (int r = 0; r < 4; ++r) {
                    const int kv = kv0 + t*16 + lrow;
                    const int q  = qb + lgrp*4 + r;
                    if (kv > PREFIX + q) s[t][r] = -1e30f;
                }
        }

        float tmax[4];
        #pragma unroll
        for (int r = 0; r < 4; ++r) tmax[r] = fmaxf(s[0][r], s[1][r]);
        #pragma unroll
        for (int off = 1; off <= 8; off <<= 1)
            #pragma unroll
            for (int r = 0; r < 4; ++r) tmax[r] = fmaxf(tmax[r], __shfl_xor(tmax[r], off, 64));

        float f[4];
        #pragma unroll
        for (int r = 0; r < 4; ++r) {
            const float mn = fmaxf(m_r[r], tmax[r]);
            f[r] = __expf(m_r[r] - mn);
            m_r[r] = mn;
        }
        #pragma unroll
        for (int t = 0; t < 2; ++t)
            #pragma unroll
            for (int r = 0; r < 4; ++r) s[t][r] = __expf(s[t][r] - m_r[r]);

        float rs[4];
        #pragma unroll
        for (int r = 0; r < 4; ++r) rs[r] = s[0][r] + s[1][r];
        #pragma unroll
        for (int off = 1; off <= 8; off <<= 1)
            #pragma unroll
            for (int r = 0; r < 4; ++r) rs[r] += __shfl_xor(rs[r], off, 64);
        #pragma unroll
        for (int r = 0; r < 4; ++r) l_r[r] = l_r[r] * f[r] + rs[r];
        #pragma unroll
        for (int n = 0; n < 4; ++n)
            #pragma unroll
            for (int r = 0; r < 4; ++r) oacc[n][r] *= f[r];

        #pragma unroll
        for (int t = 0; t < 2; ++t)
            #pragma unroll
            for (int r = 0; r < 4; ++r)
                sPf[w][lgrp*4 + r][t*16 + lrow] = f2bf(s[t][r]);
        asm volatile("s_waitcnt lgkmcnt(0)" ::: "memory");
        __builtin_amdgcn_sched_barrier(0);

        const short8 pa = *(const short8*)&sPf[w][lrow][lgrp*8];
        #pragma unroll
        for (int n = 0; n < 4; ++n) {
            const short8 vb = *(const short8*)&sVt[n*16 + lrow][lgrp*8];
            oacc[n] = __builtin_amdgcn_mfma_f32_16x16x32_bf16(pa, vb, oacc[n], 0, 0, 0);
        }
    }

    float inv[4];
    #pragma unroll
    for (int r = 0; r < 4; ++r) inv[r] = 1.0f / l_r[r];
    float* op = O + ((size_t)h * QL + qb) * DH;
    #pragma unroll
    for (int n = 0; n < 4; ++n)
        #pragma unroll
        for (int r = 0; r < 4; ++r)
            op[(lgrp*4 + r) * DH + n*16 + lrow] = oacc[n][r] * inv[r];
}

extern "C" void kernel_launch(void* const* d_in, const int* in_sizes, int n_in,
                              void* d_out, int out_size, void* d_ws, size_t ws_size,
                              hipStream_t stream) {
    const float* Q = (const float*)d_in[0];
    const float* K = (const float*)d_in[1];
    const float* V = (const float*)d_in[2];
    float* O = (float*)d_out;
    const size_t KVWS  = (size_t)NH * NTILES * TILE_US * 2;   // 25.17 MB
    const size_t PART1 = (size_t)NH * QL * 68 * 4;            // 8.91 MB / split
    ushort* wsKV = (ushort*)d_ws;
    float*  part = (float*)((char*)d_ws + KVWS);

    if (ws_size >= KVWS + 3 * PART1) {
        hipLaunchKernelGGL(convK, dim3(2048), dim3(256), 0, stream, K, wsKV);
        hipLaunchKernelGGL(convV, dim3(1024), dim3(512), 0, stream, V, wsKV);
        hipLaunchKernelGGL(sdpa_main<3>, dim3(512 * 3), dim3(128), 0, stream, Q, wsKV, O, part);
        hipLaunchKernelGGL(combine<3>, dim3(8192), dim3(256), 0, stream, part, O);
    } else if (ws_size >= KVWS + 2 * PART1) {
        hipLaunchKernelGGL(convK, dim3(2048), dim3(256), 0, stream, K, wsKV);
        hipLaunchKernelGGL(convV, dim3(1024), dim3(512), 0, stream, V, wsKV);
        hipLaunchKernelGGL(sdpa_main<2>, dim3(512 * 2), dim3(128), 0, stream, Q, wsKV, O, part);
        hipLaunchKernelGGL(combine<2>, dim3(8192), dim3(256), 0, stream, part, O);
    } else if (ws_size >= KVWS) {
        hipLaunchKernelGGL(convK, dim3(2048), dim3(256), 0, stream, K, wsKV);
        hipLaunchKernelGGL(convV, dim3(1024), dim3(512), 0, stream, V, wsKV);
        hipLaunchKernelGGL(sdpa_main<1>, dim3(512), dim3(128), 0, stream, Q, wsKV, O, part);
    } else {
        hipLaunchKernelGGL(sdpa_fallback, dim3(32, 16), dim3(256), 0, stream, Q, K, V, O);
    }
}

// Round 5
// 71.693 us; speedup vs baseline: 3.7758x; 1.4268x over previous
//
#include <hip/hip_runtime.h>
#include <hip/hip_bf16.h>

#define NH 16
#define QL 2048
#define KVL 4096
#define DH 64
#define PREFIX (KVL - QL)
#define NT 64                 // kv tiles of 64
#define TUS 8192              // ushorts per tile: K frags 4096 | V frags 4096
#define NS 2                  // kv splits per q-block
// scale * log2(e): softmax in base-2 domain (v_exp_f32 is exp2)
#define SCALE 0.18033688011112043f

typedef __attribute__((ext_vector_type(8))) _Float16 f16x8;
typedef __attribute__((ext_vector_type(8))) short short8;
typedef __attribute__((ext_vector_type(4))) float f32x4;
typedef __attribute__((ext_vector_type(16))) float f32x16;
typedef unsigned int u32;

static __device__ __forceinline__ float exp2_fast(float x) {
    float r; asm("v_exp_f32 %0, %1" : "=v"(r) : "v"(x)); return r;
}
static __device__ __forceinline__ u32 pkrtz(float lo, float hi) {
    u32 r; asm("v_cvt_pkrtz_f16_f32 %0, %1, %2" : "=v"(r) : "v"(lo), "v"(hi)); return r;
}
static __device__ __forceinline__ void plswap(u32& x, u32& y) {
    asm("v_permlane32_swap_b32 %0, %1" : "+v"(x), "+v"(y));
}
#define MFMAH(a, b, c) __builtin_amdgcn_mfma_f32_32x32x16_f16(a, b, c, 0, 0, 0)

static __device__ __forceinline__ ushort f2bf(float x) {
    union { float f; u32 u; } v; v.f = x;
    u32 r = v.u + 0x7fffu + ((v.u >> 16) & 1u);
    return (ushort)(r >> 16);
}
static __device__ __forceinline__ float bf2f(ushort h) {
    union { u32 u; float f; } v; v.u = ((u32)h) << 16;
    return v.f;
}

// ---- precompute K: ws[h][tile][fidx=t*4+ks][lane] = f16 K[32t+lq][16ks+8hi+0..7] ----
__global__ void convK2(const float* __restrict__ K, ushort* __restrict__ ws) {
    const int gid  = blockIdx.x * 256 + threadIdx.x;   // 16*64*8*64 = 524288
    const int lane = gid & 63;
    const int fidx = (gid >> 6) & 7;
    const int tile = (gid >> 9) & 63;
    const int h    = gid >> 15;
    const int lq = lane & 31, hi = lane >> 5;
    const int t = fidx >> 2, ks = fidx & 3;
    const int kv = tile * 64 + t * 32 + lq;
    const float* src = K + ((size_t)h * KVL + kv) * DH + ks * 16 + hi * 8;
    const float4 a = *(const float4*)src;
    const float4 b = *(const float4*)(src + 4);
    const float v[8] = {a.x, a.y, a.z, a.w, b.x, b.y, b.z, b.w};
    f16x8 o;
    #pragma unroll
    for (int j = 0; j < 8; ++j) o[j] = (_Float16)v[j];
    *(f16x8*)(ws + (size_t)(h * NT + tile) * TUS + fidx * 512 + lane * 8) = o;
}

// ---- precompute V^T: ws[...]+4096: [fidx=dt*4+ks][lane] = f16 V[16ks+8hi+j][32dt+lq] ----
__global__ void convV2(const float* __restrict__ V, ushort* __restrict__ ws) {
    const int gid  = blockIdx.x * 256 + threadIdx.x;
    const int lane = gid & 63;
    const int fidx = (gid >> 6) & 7;
    const int tile = (gid >> 9) & 63;
    const int h    = gid >> 15;
    const int lq = lane & 31, hi = lane >> 5;
    const int dt = fidx >> 2, ks = fidx & 3;
    const int d  = dt * 32 + lq;
    const float* src = V + ((size_t)h * KVL + tile * 64 + ks * 16 + hi * 8) * DH + d;
    f16x8 o;
    #pragma unroll
    for (int j = 0; j < 8; ++j) o[j] = (_Float16)src[j * DH];
    *(f16x8*)(ws + (size_t)(h * NT + tile) * TUS + 4096 + fidx * 512 + lane * 8) = o;
}

// ==== main: 4 independent waves/block, 32 q/wave, no LDS, no barriers ====
__global__ __launch_bounds__(256, 2)
void sdpa_main(const float* __restrict__ Q, const ushort* __restrict__ ws,
               float* __restrict__ part)
{
    const int tid  = threadIdx.x;
    const int lane = tid & 63;
    const int w    = tid >> 6;
    const int lq   = lane & 31;
    const int hi   = lane >> 5;

    // block-balanced mapping: block has waves (qwA,sp0/1) + (63-qwA,sp0/1)
    const int bid = blockIdx.x;          // 512 blocks
    const int xcd = bid & 7;
    const int j   = bid >> 3;            // 0..63
    const int h   = xcd * 2 + (j & 1);
    const int qwA = j >> 1;              // 0..31
    const int qw  = (w & 1) ? (63 - qwA) : qwA;
    const int sp  = w >> 1;
    const int qb  = qw * 32;

    const int ntt = (PREFIX + qb + 32 + 63) >> 6;
    const int t0  = (ntt * sp) / NS;
    const int t1  = (ntt * (sp + 1)) / NS;

    // ---- Q fragments, f16 hi/lo split, pre-scaled by scale*log2e ----
    f16x8 qh[4], ql[4];
    {
        const float* qp = Q + ((size_t)h * QL + qb + lq) * DH + hi * 8;
        #pragma unroll
        for (int ks = 0; ks < 4; ++ks) {
            const float4 a = *(const float4*)(qp + ks * 16);
            const float4 b = *(const float4*)(qp + ks * 16 + 4);
            const float v[8] = {a.x, a.y, a.z, a.w, b.x, b.y, b.z, b.w};
            #pragma unroll
            for (int jj = 0; jj < 8; ++jj) {
                const float x = v[jj] * SCALE;
                const _Float16 xh = (_Float16)x;
                qh[ks][jj] = xh;
                ql[ks][jj] = (_Float16)(x - (float)xh);
            }
        }
    }

    f32x16 oacc[2];
    #pragma unroll
    for (int dt = 0; dt < 2; ++dt)
        #pragma unroll
        for (int r = 0; r < 16; ++r) oacc[dt][r] = 0.f;
    float m = 0.0f, lsum = 0.f;

    const ushort* tb = ws + (size_t)h * NT * TUS + (size_t)t0 * TUS;

    for (int it = t0; it < t1; ++it, tb += TUS) {
        // ---- coalesced frag loads straight from L2 (no LDS) ----
        f16x8 kf[8], vf[8];
        #pragma unroll
        for (int f = 0; f < 8; ++f) kf[f] = *(const f16x8*)(tb + f * 512 + lane * 8);
        #pragma unroll
        for (int f = 0; f < 8; ++f) vf[f] = *(const f16x8*)(tb + 4096 + f * 512 + lane * 8);

        // ---- QK^T swapped (2-term f16 split): sT[t] = S[kv=32t+c(r)+4hi][q=lq] ----
        f32x16 sT[2];
        #pragma unroll
        for (int t = 0; t < 2; ++t)
            #pragma unroll
            for (int r = 0; r < 16; ++r) sT[t][r] = 0.f;

        __builtin_amdgcn_s_setprio(1);
        #pragma unroll
        for (int ks = 0; ks < 4; ++ks) {
            sT[0] = MFMAH(kf[ks],     qh[ks], sT[0]);
            sT[1] = MFMAH(kf[4 + ks], qh[ks], sT[1]);
            sT[0] = MFMAH(kf[ks],     ql[ks], sT[0]);
            sT[1] = MFMAH(kf[4 + ks], ql[ks], sT[1]);
        }
        __builtin_amdgcn_s_setprio(0);

        // ---- causal mask (boundary tiles only; wave-uniform branch) ----
        const int kv0 = it * 64;
        if (kv0 + 64 > PREFIX + qb) {
            const int kvlim = PREFIX + qb + lq - kv0;
            #pragma unroll
            for (int t = 0; t < 2; ++t)
                #pragma unroll
                for (int r = 0; r < 16; ++r) {
                    const int kvl = t * 32 + (r & 3) + 8 * (r >> 2) + 4 * hi;
                    if (kvl > kvlim) sT[t][r] = -1e30f;
                }
        }

        // ---- online softmax, base-2, defer-max (THR=8) ----
        float mx = sT[0][0];
        #pragma unroll
        for (int t = 0; t < 2; ++t)
            #pragma unroll
            for (int r = 0; r < 16; ++r) mx = fmaxf(mx, sT[t][r]);
        mx = fmaxf(mx, __shfl_xor(mx, 32));
        if (__any(mx > m + 8.0f)) {
            const float mn  = fmaxf(m, mx);
            const float fsc = exp2_fast(m - mn);
            lsum *= fsc;
            #pragma unroll
            for (int dt = 0; dt < 2; ++dt)
                #pragma unroll
                for (int r = 0; r < 16; ++r) oacc[dt][r] *= fsc;
            m = mn;
        }
        float rs = 0.f;
        #pragma unroll
        for (int t = 0; t < 2; ++t)
            #pragma unroll
            for (int r = 0; r < 16; ++r) {
                const float p = exp2_fast(sT[t][r] - m);
                sT[t][r] = p;
                rs += p;
            }
        lsum += rs;

        // ---- P -> f16 frags fully in-register: cvt_pkrtz + permlane32_swap ----
        f16x8 pb[4];
        #pragma unroll
        for (int t = 0; t < 2; ++t) {
            u32 x0 = pkrtz(sT[t][0],  sT[t][1]);
            u32 x1 = pkrtz(sT[t][2],  sT[t][3]);
            u32 y0 = pkrtz(sT[t][4],  sT[t][5]);
            u32 y1 = pkrtz(sT[t][6],  sT[t][7]);
            u32 x2 = pkrtz(sT[t][8],  sT[t][9]);
            u32 x3 = pkrtz(sT[t][10], sT[t][11]);
            u32 y2 = pkrtz(sT[t][12], sT[t][13]);
            u32 y3 = pkrtz(sT[t][14], sT[t][15]);
            plswap(x0, y0); plswap(x1, y1);
            plswap(x2, y2); plswap(x3, y3);
            union { u32 u[4]; f16x8 v; } p0, p1;
            p0.u[0] = x0; p0.u[1] = x1; p0.u[2] = y0; p0.u[3] = y1;
            p1.u[0] = x2; p1.u[1] = x3; p1.u[2] = y2; p1.u[3] = y3;
            pb[t * 2 + 0] = p0.v;
            pb[t * 2 + 1] = p1.v;
        }

        // ---- PV: oacc[dt] += V^T-frag * P^T-frag ----
        __builtin_amdgcn_s_setprio(1);
        #pragma unroll
        for (int ks = 0; ks < 4; ++ks) {
            oacc[0] = MFMAH(vf[ks],     pb[ks], oacc[0]);
            oacc[1] = MFMAH(vf[4 + ks], pb[ks], oacc[1]);
        }
        __builtin_amdgcn_s_setprio(0);
    }

    // ---- epilogue: write partial (O^T rows, m, l) ----
    const float ltot = lsum + __shfl_xor(lsum, 32);
    float* pr = part + ((size_t)(sp * NH + h) * QL + qb + lq) * 68;
    #pragma unroll
    for (int dt = 0; dt < 2; ++dt)
        #pragma unroll
        for (int a = 0; a < 4; ++a) {
            f32x4 o;
            #pragma unroll
            for (int jj = 0; jj < 4; ++jj) o[jj] = oacc[dt][a * 4 + jj];
            *(f32x4*)(pr + dt * 32 + a * 8 + hi * 4) = o;
        }
    if (hi == 0) { pr[64] = m; pr[65] = ltot; }
}

// ---- combine NS partials: O = sum_j 2^(m_j-M) O_j / sum_j 2^(m_j-M) l_j ----
__global__ void combine2(const float* __restrict__ part, float* __restrict__ O) {
    const int row = blockIdx.x * 4 + (threadIdx.x >> 6);  // h*QL + q
    const int d   = threadIdx.x & 63;
    const float* p0 = part + (size_t)row * 68;
    const float* p1 = part + ((size_t)NH * QL + row) * 68;
    const float m0 = p0[64], l0 = p0[65];
    const float m1 = p1[64], l1 = p1[65];
    const float M  = fmaxf(m0, m1);
    const float w0 = exp2f(m0 - M), w1 = exp2f(m1 - M);
    O[(size_t)row * DH + d] = (w0 * p0[d] + w1 * p1[d]) / (w0 * l0 + w1 * l1);
}

// ================= fallback (round-1 kernel, proven, no ws needed) =================
#define QT 64
#define KBf 32
#define KSTR 72
#define VSTR 40
#define PSTR 40
#define SCALE_E 0.125f

__global__ __launch_bounds__(256, 2)
void sdpa_fallback(const float* __restrict__ Q, const float* __restrict__ K,
                   const float* __restrict__ V, float* __restrict__ O)
{
    __shared__ ushort sKh[KBf][KSTR];
    __shared__ ushort sKl[KBf][KSTR];
    __shared__ ushort sVt[DH][VSTR];
    __shared__ ushort sPf[4][16][PSTR];

    const int tid  = threadIdx.x;
    const int lane = tid & 63;
    const int w    = tid >> 6;
    const int h    = blockIdx.y;
    const int q0   = blockIdx.x * QT;
    const int qb   = q0 + w * 16;
    const int lrow = lane & 15;
    const int lgrp = lane >> 4;

    short8 qh[2], ql[2];
    {
        const float* qp = Q + ((size_t)h * QL + (qb + lrow)) * DH;
        #pragma unroll
        for (int dh = 0; dh < 2; ++dh) {
            const int d0 = dh * 32 + lgrp * 8;
            #pragma unroll
            for (int jj = 0; jj < 8; ++jj) {
                float x = qp[d0 + jj] * SCALE_E;
                ushort hb = f2bf(x);
                qh[dh][jj] = (short)hb;
                ql[dh][jj] = (short)f2bf(x - bf2f(hb));
            }
        }
    }

    f32x4 oacc[4];
    float m_r[4], l_r[4];
    #pragma unroll
    for (int n = 0; n < 4; ++n) { oacc[n][0]=0.f; oacc[n][1]=0.f; oacc[n][2]=0.f; oacc[n][3]=0.f; }
    #pragma unroll
    for (int r = 0; r < 4; ++r) { m_r[r] = -1e30f; l_r[r] = 0.f; }

    const int nkv = min(KVL, PREFIX + q0 + QT);

    for (int kv0 = 0; kv0 < nkv; kv0 += KBf) {
        __syncthreads();
        {
            const int r  = tid >> 3;
            const int d0 = (tid & 7) * 8;
            const float* kp = K + ((size_t)h * KVL + (kv0 + r)) * DH + d0;
            const float* vp = V + ((size_t)h * KVL + (kv0 + r)) * DH + d0;
            short8 vh, vl;
            #pragma unroll
            for (int jj = 0; jj < 8; ++jj) {
                float x = kp[jj];
                ushort hb = f2bf(x);
                vh[jj] = (short)hb;
                vl[jj] = (short)f2bf(x - bf2f(hb));
            }
            *(short8*)&sKh[r][d0] = vh;
            *(short8*)&sKl[r][d0] = vl;
            #pragma unroll
            for (int jj = 0; jj < 8; ++jj)
                sVt[d0 + jj][r] = f2bf(vp[jj]);
        }
        __syncthreads();

        f32x4 s[2];
        #pragma unroll
        for (int t = 0; t < 2; ++t) { s[t][0]=0.f; s[t][1]=0.f; s[t][2]=0.f; s[t][3]=0.f; }
        #pragma unroll
        for (int t = 0; t < 2; ++t) {
            #pragma unroll
            for (int dh = 0; dh < 2; ++dh) {
                const short8 kh = *(const short8*)&sKh[t*16 + lrow][dh*32 + lgrp*8];
                const short8 kl = *(const short8*)&sKl[t*16 + lrow][dh*32 + lgrp*8];
                s[t] = __builtin_amdgcn_mfma_f32_16x16x32_bf16(qh[dh], kh, s[t], 0, 0, 0);
                s[t] = __builtin_amdgcn_mfma_f32_16x16x32_bf16(qh[dh], kl, s[t], 0, 0, 0);
                s[t] = __builtin_amdgcn_mfma_f32_16x16x32_bf16(ql[dh], kh, s[t], 0, 0, 0);
            }
        }

        if (kv0 + KBf > PREFIX + qb) {
            #pragma unroll
            for (int t = 0; t < 2; ++t)
                #pragma unroll
                for (int r = 0; r < 4; ++r) {
                    const int kv = kv0 + t*16 + lrow;
                    const int q  = qb + lgrp*4 + r;
                    if (kv > PREFIX + q) s[t][r] = -1e30f;
                }
        }

        float tmax[4];
        #pragma unroll
        for (int r = 0; r < 4; ++r) tmax[r] = fmaxf(s[0][r], s[1][r]);
        #pragma unroll
        for (int off = 1; off <= 8; off <<= 1)
            #pragma unroll
            for (int r = 0; r < 4; ++r) tmax[r] = fmaxf(tmax[r], __shfl_xor(tmax[r], off, 64));

        float f[4];
        #pragma unroll
        for (int r = 0; r < 4; ++r) {
            const float mn = fmaxf(m_r[r], tmax[r]);
            f[r] = __expf(m_r[r] - mn);
            m_r[r] = mn;
        }
        #pragma unroll
        for (int t = 0; t < 2; ++t)
            #pragma unroll
            for (int r = 0; r < 4; ++r) s[t][r] = __expf(s[t][r] - m_r[r]);

        float rs[4];
        #pragma unroll
        for (int r = 0; r < 4; ++r) rs[r] = s[0][r] + s[1][r];
        #pragma unroll
        for (int off = 1; off <= 8; off <<= 1)
            #pragma unroll
            for (int r = 0; r < 4; ++r) rs[r] += __shfl_xor(rs[r], off, 64);
        #pragma unroll
        for (int r = 0; r < 4; ++r) l_r[r] = l_r[r] * f[r] + rs[r];
        #pragma unroll
        for (int n = 0; n < 4; ++n)
            #pragma unroll
            for (int r = 0; r < 4; ++r) oacc[n][r] *= f[r];

        #pragma unroll
        for (int t = 0; t < 2; ++t)
            #pragma unroll
            for (int r = 0; r < 4; ++r)
                sPf[w][lgrp*4 + r][t*16 + lrow] = f2bf(s[t][r]);
        asm volatile("s_waitcnt lgkmcnt(0)" ::: "memory");
        __builtin_amdgcn_sched_barrier(0);

        const short8 pa = *(const short8*)&sPf[w][lrow][lgrp*8];
        #pragma unroll
        for (int n = 0; n < 4; ++n) {
            const short8 vb = *(const short8*)&sVt[n*16 + lrow][lgrp*8];
            oacc[n] = __builtin_amdgcn_mfma_f32_16x16x32_bf16(pa, vb, oacc[n], 0, 0, 0);
        }
    }

    float inv[4];
    #pragma unroll
    for (int r = 0; r < 4; ++r) inv[r] = 1.0f / l_r[r];
    float* op = O + ((size_t)h * QL + qb) * DH;
    #pragma unroll
    for (int n = 0; n < 4; ++n)
        #pragma unroll
        for (int r = 0; r < 4; ++r)
            op[(lgrp*4 + r) * DH + n*16 + lrow] = oacc[n][r] * inv[r];
}

extern "C" void kernel_launch(void* const* d_in, const int* in_sizes, int n_in,
                              void* d_out, int out_size, void* d_ws, size_t ws_size,
                              hipStream_t stream) {
    const float* Q = (const float*)d_in[0];
    const float* K = (const float*)d_in[1];
    const float* V = (const float*)d_in[2];
    float* O = (float*)d_out;
    const size_t KVWS = (size_t)NH * NT * TUS * 2;       // 16.78 MB
    const size_t PART = (size_t)NH * QL * 68 * 4;        // 8.91 MB / split

    if (ws_size >= KVWS + NS * PART) {
        ushort* wsKV = (ushort*)d_ws;
        float*  part = (float*)((char*)d_ws + KVWS);
        hipLaunchKernelGGL(convK2, dim3(2048), dim3(256), 0, stream, K, wsKV);
        hipLaunchKernelGGL(convV2, dim3(2048), dim3(256), 0, stream, V, wsKV);
        hipLaunchKernelGGL(sdpa_main, dim3(512), dim3(256), 0, stream, Q, wsKV, part);
        hipLaunchKernelGGL(combine2, dim3(8192), dim3(256), 0, stream, part, O);
    } else {
        hipLaunchKernelGGL(sdpa_fallback, dim3(32, 16), dim3(256), 0, stream, Q, K, V, O);
    }
}